// Round 14
// baseline (220.984 us; speedup 1.0000x reference)
//
#include <hip/hip_runtime.h>
#include <hip/hip_bf16.h>

// MaskedMSA: B=8, T=1024, C=768, H=12, D=64, M=8, N=8200
// R24: qkv occupancy via SMALLER TILE (mechanism from R23 counters: qkv is
//      grid/TLP-starved — 4.5 blocks/CU, reg file 128/wave caps 16 waves/CU,
//      no pipe >40%; all 4 scheduling attacks failed because they cut TLP).
//      New qkv core: BM=64 x BN=128, 4 waves (32x64/wave, acc[2]=32 AGPR),
//      grid 1152->2304 blocks (9/CU), LDS 12KB, unified regs ~82/wave ->
//      6 waves/SIMD cap. Same serial stage->sync->compute->sync + swizzle
//      (row offsets all %32==0 so key=(l31>>1)&3 unchanged). 1-D grid decode:
//      q/k bid=tn*128+tm (same-tm = same XCD); V bid=1536+wv*64+tv.
//      proj/attn/split = R23 exact (isolation).

#define BB 8
#define TT 1024
#define CC 768
#define HH 12
#define DD 64
#define MM 8
#define NTOK (BB*TT)            // 8192
#define NX (NTOK*CC)            // 6291456
#define NWQ (3*CC*CC)           // 1769472
#define NWP (CC*CC)             // 589824
#define QSCALE 0.18033688011112042f   // 0.125 * log2(e)

typedef short bf16x4 __attribute__((ext_vector_type(4)));
typedef short bf16x8 __attribute__((ext_vector_type(8)));
typedef float f32x4  __attribute__((ext_vector_type(4)));
typedef float f32x16 __attribute__((ext_vector_type(16)));
typedef unsigned int u32x2 __attribute__((ext_vector_type(2)));

__device__ __forceinline__ void gld16(const void* g, void* l) {
  __builtin_amdgcn_global_load_lds(
      (const __attribute__((address_space(1))) void*)g,
      (__attribute__((address_space(3))) void*)l, 16, 0, 0);
}

// RNE fp32->bf16
__device__ __forceinline__ short bf_rne(float f) {
  unsigned u = __float_as_uint(f);
  return (short)((u + 0x7FFFu + ((u >> 16) & 1u)) >> 16);
}
// RNE fp32->bf16 hi, residual -> bf16 lo
__device__ __forceinline__ short bf_split(float f, short& lo) {
  unsigned u = __float_as_uint(f);
  unsigned hb = (u + 0x7FFFu + ((u >> 16) & 1u)) >> 16;
  float r = f - __uint_as_float(hb << 16);
  lo = bf_rne(r);
  return (short)hb;
}

// ------- split: x,Wqkv -> bf16 hi; Wp -> bf16 hi+lo; also zero out head -----
// Grid-stride at 2048 blocks (~4 items/thread).
__global__ __launch_bounds__(256) void split_inputs(
    const float* __restrict__ x, const float* __restrict__ wq,
    const float* __restrict__ wp,
    short* __restrict__ xh, short* __restrict__ wqh,
    short* __restrict__ wph, short* __restrict__ wpl,
    float* __restrict__ out) {
  const int G0 = NX/4, G1 = G0 + NWQ/4, G2 = G1 + NWP/4;
  const int i0 = blockIdx.x * 256 + threadIdx.x;
  if (i0 < MM*CC/4) {   // zero the first M rows of out (6144 floats)
    float4 z = {0.f, 0.f, 0.f, 0.f};
    ((float4*)out)[i0] = z;
  }
  for (int i = i0; i < G2; i += 2048 * 256) {
    if (i < G1) {
      const float* src = (i < G0) ? x : wq;
      short* dh = (i < G0) ? xh : wqh;
      int li = (i < G0) ? i : i - G0;
      float4 v = *(const float4*)(src + (size_t)li * 4);
      short4 h;
      h.x = bf_rne(v.x); h.y = bf_rne(v.y); h.z = bf_rne(v.z); h.w = bf_rne(v.w);
      *(short4*)(dh + (size_t)li * 4) = h;
    } else {
      int li = i - G1;
      float4 v = *(const float4*)(wp + (size_t)li * 4);
      short4 h, l;
      h.x = bf_split(v.x, l.x);
      h.y = bf_split(v.y, l.y);
      h.z = bf_split(v.z, l.z);
      h.w = bf_split(v.w, l.w);
      *(short4*)(wph + (size_t)li * 4) = h;
      *(short4*)(wpl + (size_t)li * 4) = l;
    }
  }
}

// ---------------- TRIPLE MFMA GEMM core (proj) — R16/R23 exact -------------
// LDS layout swizzle: physical slot (row, s) holds global 16B-slot s^((row>>1)&3).
template<bool TRIPLE>
__device__ __forceinline__ void gemm_core_768(
    const short* __restrict__ ah_g, const short* __restrict__ al_g,
    const short* __restrict__ bh_g, const short* __restrict__ bl_g,
    short* Ah, short* Al, short* Bh, short* Bl,
    int m0, int n0, f32x16 (&acc)[2][2],
    int& wm_o, int& wn_o) {
  const int tid = threadIdx.x;
  const int w = tid >> 6, ln = tid & 63;
  const int wm = (w >> 1) * 64, wn = (w & 1) * 64;
  const int sr = ln >> 2;
  const int sc = (((ln & 3) ^ ((ln >> 3) & 3))) * 8;   // swizzled source slot
  const int l31 = ln & 31, lhi = ln >> 5;
  const int key = (l31 >> 1) & 3;                      // == (row>>1)&3
  const int c0 = 2*w, c1 = 2*w + 1;
  const short* gAh0 = ah_g + (size_t)(m0 + c0*16 + sr)*CC + sc;
  const short* gAh1 = ah_g + (size_t)(m0 + c1*16 + sr)*CC + sc;
  const short* gBh0 = bh_g + (size_t)(n0 + c0*16 + sr)*CC + sc;
  const short* gBh1 = bh_g + (size_t)(n0 + c1*16 + sr)*CC + sc;
  const short* gAl0 = TRIPLE ? al_g + (size_t)(m0 + c0*16 + sr)*CC + sc : nullptr;
  const short* gAl1 = TRIPLE ? al_g + (size_t)(m0 + c1*16 + sr)*CC + sc : nullptr;
  const short* gBl0 = TRIPLE ? bl_g + (size_t)(n0 + c0*16 + sr)*CC + sc : nullptr;
  const short* gBl1 = TRIPLE ? bl_g + (size_t)(n0 + c1*16 + sr)*CC + sc : nullptr;
  #pragma unroll
  for (int i = 0; i < 2; i++)
    #pragma unroll
    for (int j = 0; j < 2; j++)
      #pragma unroll
      for (int r = 0; r < 16; r++) acc[i][j][r] = 0.f;

  for (int it = 0; it < 24; ++it) {
    const int ko = it * 32;
    gld16(gAh0 + ko, &Ah[c0*512]);
    gld16(gAh1 + ko, &Ah[c1*512]);
    gld16(gBh0 + ko, &Bh[c0*512]);
    gld16(gBh1 + ko, &Bh[c1*512]);
    if constexpr (TRIPLE) {
      gld16(gAl0 + ko, &Al[c0*512]);
      gld16(gAl1 + ko, &Al[c1*512]);
      gld16(gBl0 + ko, &Bl[c0*512]);
      gld16(gBl1 + ko, &Bl[c1*512]);
    }
    __syncthreads();
    bf16x8 a_h[2][2], b_h[2][2];
    #pragma unroll
    for (int t = 0; t < 2; ++t)
      #pragma unroll
      for (int kc = 0; kc < 2; ++kc) {
        const int sA = ((kc*2 + lhi) ^ key) * 8;
        a_h[t][kc] = *(const bf16x8*)&Ah[(wm + t*32 + l31)*32 + sA];
        b_h[t][kc] = *(const bf16x8*)&Bh[(wn + t*32 + l31)*32 + sA];
      }
    if constexpr (TRIPLE) {
      bf16x8 a_l[2][2], b_l[2][2];
      #pragma unroll
      for (int t = 0; t < 2; ++t)
        #pragma unroll
        for (int kc = 0; kc < 2; ++kc) {
          const int sA = ((kc*2 + lhi) ^ key) * 8;
          a_l[t][kc] = *(const bf16x8*)&Al[(wm + t*32 + l31)*32 + sA];
          b_l[t][kc] = *(const bf16x8*)&Bl[(wn + t*32 + l31)*32 + sA];
        }
      #pragma unroll
      for (int mt = 0; mt < 2; ++mt)
        #pragma unroll
        for (int nt = 0; nt < 2; ++nt)
          #pragma unroll
          for (int kc = 0; kc < 2; ++kc) {
            acc[mt][nt] = __builtin_amdgcn_mfma_f32_32x32x16_bf16(
                a_h[mt][kc], b_h[nt][kc], acc[mt][nt], 0, 0, 0);
            acc[mt][nt] = __builtin_amdgcn_mfma_f32_32x32x16_bf16(
                a_h[mt][kc], b_l[nt][kc], acc[mt][nt], 0, 0, 0);
            acc[mt][nt] = __builtin_amdgcn_mfma_f32_32x32x16_bf16(
                a_l[mt][kc], b_h[nt][kc], acc[mt][nt], 0, 0, 0);
          }
    } else {
      #pragma unroll
      for (int mt = 0; mt < 2; ++mt)
        #pragma unroll
        for (int nt = 0; nt < 2; ++nt)
          #pragma unroll
          for (int kc = 0; kc < 2; ++kc)
            acc[mt][nt] = __builtin_amdgcn_mfma_f32_32x32x16_bf16(
                a_h[mt][kc], b_h[nt][kc], acc[mt][nt], 0, 0, 0);
    }
    __syncthreads();
  }
  wm_o = wm; wn_o = wn;
}

// ---------- qkv GEMM core: BM=64 x BN=128, 4 waves, 12KB LDS ---------------
// Wave w: A rows [wm, wm+32), B rows [wn, wn+64); acc[nt] covers cols
// wn+nt*32. Swizzle identical (all row offsets %32==0 -> key=(l31>>1)&3).
__device__ __forceinline__ void gemm_core_64x128(
    const short* __restrict__ a_g, const short* __restrict__ b_g,
    short* Ah, short* Bh, int m0, int n0, f32x16 (&acc)[2],
    int& wm_o, int& wn_o) {
  const int tid = threadIdx.x;
  const int w = tid >> 6, ln = tid & 63;
  const int wm = (w >> 1) * 32, wn = (w & 1) * 64;
  const int l31 = ln & 31, lhi = ln >> 5;
  const int key = (l31 >> 1) & 3;

  // A staging: wave w rows w*16 + (ln>>2), lane slot ln&3 (linear dest).
  const int rA = w*16 + (ln >> 2);
  const short* gA = a_g + (size_t)(m0 + rA)*CC
                        + ((ln & 3) ^ ((rA >> 1) & 3)) * 8;
  // B staging: wave w rows w*32+(ln>>2) and w*32+16+(ln>>2).
  const int rB0 = w*32 + (ln >> 2), rB1 = rB0 + 16;
  const short* gB0 = b_g + (size_t)(n0 + rB0)*CC
                         + ((ln & 3) ^ ((rB0 >> 1) & 3)) * 8;
  const short* gB1 = b_g + (size_t)(n0 + rB1)*CC
                         + ((ln & 3) ^ ((rB1 >> 1) & 3)) * 8;

  #pragma unroll
  for (int j = 0; j < 2; j++)
    #pragma unroll
    for (int r = 0; r < 16; r++) acc[j][r] = 0.f;

  for (int it = 0; it < 24; ++it) {
    const int ko = it * 32;
    gld16(gA  + ko, &Ah[w*512]);
    gld16(gB0 + ko, &Bh[w*1024]);
    gld16(gB1 + ko, &Bh[w*1024 + 512]);
    __syncthreads();
    bf16x8 a_h[2], b_h[2][2];
    #pragma unroll
    for (int kc = 0; kc < 2; ++kc) {
      const int sA = ((kc*2 + lhi) ^ key) * 8;
      a_h[kc]    = *(const bf16x8*)&Ah[(wm + l31)*32 + sA];
      b_h[0][kc] = *(const bf16x8*)&Bh[(wn + l31)*32 + sA];
      b_h[1][kc] = *(const bf16x8*)&Bh[(wn + 32 + l31)*32 + sA];
    }
    #pragma unroll
    for (int nt = 0; nt < 2; ++nt)
      #pragma unroll
      for (int kc = 0; kc < 2; ++kc)
        acc[nt] = __builtin_amdgcn_mfma_f32_32x32x16_bf16(
            a_h[kc], b_h[nt][kc], acc[nt], 0, 0, 0);
    __syncthreads();
  }
  wm_o = wm; wn_o = wn;
}

// QKV: 1-D grid of 2304 blocks.
//   bid < 1536: q/k.  bid = tn*128 + tm; m0 = tm*64 (tokens), n0 = tn*128
//     (features in [0,1536)). Same-tm blocks differ by 128 (%8==0 -> same XCD).
//   bid >= 1536: V (swapped). vb = bid-1536 = wv*64 + tv; A = Wv rows
//     1536+wv*64, B = tokens tv*128. Same-tv blocks differ by 64 (%8==0).
__global__ __launch_bounds__(256, 6) void qkv_mfma(
    const short* __restrict__ xh, const short* __restrict__ wqh,
    const int* __restrict__ mask,
    short* __restrict__ qb, short* __restrict__ kb, short* __restrict__ vbt) {
  __shared__ __align__(16) short Ah[64*32], Bh[128*32];   // 12 KB
  f32x16 acc[2];
  int wm, wn;
  const int ln = threadIdx.x & 63;
  const int l31 = ln & 31, lhi = ln >> 5;
  const int bid = blockIdx.x;

  if (bid < 1536) {
    const int tn = bid >> 7, tm = bid & 127;
    const int m0 = tm * 64, n0 = tn * 128;
    gemm_core_64x128(xh, wqh, Ah, Bh, m0, n0, acc, wm, wn);
    short* dst = (n0 < CC) ? qb : kb;
    const float qs = (n0 < CC) ? QSCALE : 1.f;
    const int nb = (n0 < CC) ? n0 : n0 - CC;
    #pragma unroll
    for (int reg = 0; reg < 16; ++reg) {
      int row = m0 + wm + 4*lhi + (reg & 3) + 8*(reg >> 2);
      int mk = mask[row];
      int b = row >> 10, t = row & 1023;
      size_t rb = ((size_t)b * HH) * TT;
      #pragma unroll
      for (int nt = 0; nt < 2; ++nt) {
        int gnb = nb + wn + nt*32 + l31;
        int h = gnb >> 6, d = gnb & 63;
        float v = mk ? acc[nt][reg] * qs : 0.f;
        dst[((rb + (size_t)h * TT) + t) * DD + d] = bf_rne(v);
      }
    }
  } else {
    const int vb = bid - 1536;
    const int wv = vb >> 6, tv = vb & 63;
    const int m0w = 2*CC + wv*64;        // weight rows (absolute in Wqkv)
    const int t0 = tv * 128;             // token base
    gemm_core_64x128(wqh, xh, Ah, Bh, m0w, t0, acc, wm, wn);
    const int b = t0 >> 10, tb = t0 & 1023;
    #pragma unroll
    for (int reg = 0; reg < 16; ++reg) {
      int f = wv*64 + wm + 4*lhi + (reg & 3) + 8*(reg >> 2);
      int h = f >> 6, d = f & 63;
      short* drow = vbt + (((size_t)(b*HH + h)*DD) + d)*TT + tb;
      #pragma unroll
      for (int nt = 0; nt < 2; ++nt) {
        int tk = wn + nt*32 + l31;
        int mk = mask[t0 + tk];
        drow[tk] = bf_rne(mk ? acc[nt][reg] : 0.f);
      }
    }
  }
}

// Proj (bf16x3): add bias, mask, write to out rows M..M+8191. (R23 exact)
// Grid transposed: x = m-block (XCD grouping), y = n-block.
__global__ __launch_bounds__(256) void proj_mfma(
    const short* __restrict__ ah_g, const short* __restrict__ al_g,
    const short* __restrict__ bh_g, const short* __restrict__ bl_g,
    const int* __restrict__ mask, const float* __restrict__ bp,
    float* __restrict__ out) {
  __shared__ __align__(16) short Ah[128*32], Al[128*32];
  __shared__ __align__(16) short Bh[128*32], Bl[128*32];   // 32 KB
  const int m0 = blockIdx.x * 128, n0 = blockIdx.y * 128;
  f32x16 acc[2][2];
  int wm, wn;
  gemm_core_768<true>(ah_g, al_g, bh_g, bl_g, Ah, Al, Bh, Bl, m0, n0, acc, wm, wn);
  const int ln = threadIdx.x & 63;
  const int l31 = ln & 31, lhi = ln >> 5;
  #pragma unroll
  for (int mt = 0; mt < 2; ++mt) {
    #pragma unroll
    for (int reg = 0; reg < 16; ++reg) {
      int row = m0 + wm + mt*32 + 4*lhi + (reg & 3) + 8*(reg >> 2);
      int mk = mask[row];
      float* orow = out + (size_t)(MM + row) * CC;
      #pragma unroll
      for (int nt = 0; nt < 2; ++nt) {
        int gn = n0 + wn + nt*32 + l31;
        orow[gn] = mk ? acc[mt][nt][reg] + bp[gn] : 0.f;
      }
    }
  }
}

// ds_read_b64_tr_b16 with compile-time immediate offset.
__device__ __forceinline__ bf16x4 tr64(unsigned addr, int imm) {
  bf16x4 r;
  asm volatile("ds_read_b64_tr_b16 %0, %1 offset:%c2"
               : "=v"(r) : "v"(addr), "i"(imm));
  return r;
}

// ------- MFMA flash attention: parity-dbuf gld16 staging, 1 barrier/iter ----
// (R23 exact)
__global__ __launch_bounds__(256, 3) void attn_mfma(
    const short* __restrict__ qb, const short* __restrict__ kb,
    const short* __restrict__ vbt, const int* __restrict__ mask,
    short* __restrict__ obh, short* __restrict__ obl) {
  __shared__ __align__(16) short Ks[2][64*64];      // 16 KB
  __shared__ __align__(16) short Vt[2][64*64];      // 16 KB
  __shared__ __align__(16) short PsT[4][2][64][16]; // [w][mt][k][q] 16 KB
  const int tid = threadIdx.x, w = tid >> 6, ln = tid & 63;
  const int fl = ln & 15, fq = ln >> 4;
  const int i = blockIdx.x;
  const int bh = i % 96;                 // XCD-grouped (96 % 8 == 0)
  const int q0 = (i / 96) * 128;
  const int b = bh / HH, h = bh % HH;
  const size_t baseK = (size_t)bh * TT * DD;   // q,k natural (t,d)
  const size_t baseV = (size_t)bh * DD * TT;   // v transposed (d,t)

  bf16x8 qf[2][2];
  #pragma unroll
  for (int mt = 0; mt < 2; ++mt)
    #pragma unroll
    for (int kc = 0; kc < 2; ++kc)
      qf[mt][kc] = *(const bf16x8*)&qb[baseK +
          (size_t)(q0 + w*32 + mt*16 + fl) * DD + kc*32 + fq*8];

  f32x4 oa[2][4];
  float lsum[2][4];
  {
    f32x4 z = {0.f, 0.f, 0.f, 0.f};
    #pragma unroll
    for (int mt = 0; mt < 2; ++mt) {
      #pragma unroll
      for (int nt = 0; nt < 4; ++nt) oa[mt][nt] = z;
      #pragma unroll
      for (int r = 0; r < 4; ++r) lsum[mt][r] = 0.f;
    }
  }

  // tr-read base: per-lane addr = base(w) + fq*256 + fl*8 bytes; imm walks
  // mt (2048), kc (1024), half (128).
  const unsigned ps_rd =
      (unsigned)(size_t)(&PsT[0][0][0][0]) + w*4096 + fq*256 + fl*8;

  // Staging: thread tid covers row r1 = tid>>3 (instr1) and r2 = r1+32
  // (instr2), physical slot tid&7; global slot = (tid&7)^(r&7).
  const int r1 = tid >> 3, r2 = r1 + 32;
  const int g1 = ((ln & 7) ^ (r1 & 7)) * 8;   // shorts (tid&7 == ln&7)
  const int g2 = ((ln & 7) ^ (r2 & 7)) * 8;
  const short* kg1 = &kb[baseK + (size_t)r1 * DD + g1];
  const short* kg2 = &kb[baseK + (size_t)r2 * DD + g2];
  const short* vg1 = &vbt[baseV + (size_t)r1 * TT + g1];
  const short* vg2 = &vbt[baseV + (size_t)r2 * TT + g2];

  auto stage = [&](int p, int kt) {
    gld16(kg1 + (size_t)kt * 64 * DD, &Ks[p][w * 512]);
    gld16(kg2 + (size_t)kt * 64 * DD, &Ks[p][2048 + w * 512]);
    gld16(vg1 + kt * 64, &Vt[p][w * 512]);
    gld16(vg2 + kt * 64, &Vt[p][2048 + w * 512]);
  };

  // Prologue: tile 0 -> buf 0.
  stage(0, 0);
  asm volatile("s_waitcnt vmcnt(0)" ::: "memory");
  __builtin_amdgcn_s_barrier();
  __builtin_amdgcn_sched_barrier(0);

  for (int kt = 0; kt < 16; ++kt) {
    const int p = kt & 1;
    // Issue next tile's async stage into the idle buffer NOW.
    if (kt < 15) stage(p ^ 1, kt + 1);

    bf16x8 kf[4][2];
    #pragma unroll
    for (int nt = 0; nt < 4; ++nt)
      #pragma unroll
      for (int kc = 0; kc < 2; ++kc) {
        const int sl = ((kc*4 + fq) ^ (fl & 7)) * 8;
        kf[nt][kc] = *(const bf16x8*)&Ks[p][(nt*16 + fl)*64 + sl];
      }

    f32x4 s[2][4];
    {
      f32x4 z = {0.f, 0.f, 0.f, 0.f};
      #pragma unroll
      for (int mt = 0; mt < 2; ++mt)
        #pragma unroll
        for (int nt = 0; nt < 4; ++nt) s[mt][nt] = z;
    }
    __builtin_amdgcn_s_setprio(1);
    #pragma unroll
    for (int mt = 0; mt < 2; ++mt)
      #pragma unroll
      for (int nt = 0; nt < 4; ++nt) {
        s[mt][nt] = __builtin_amdgcn_mfma_f32_16x16x32_bf16(
            qf[mt][0], kf[nt][0], s[mt][nt], 0, 0, 0);
        s[mt][nt] = __builtin_amdgcn_mfma_f32_16x16x32_bf16(
            qf[mt][1], kf[nt][1], s[mt][nt], 0, 0, 0);
      }
    __builtin_amdgcn_s_setprio(0);

    // vf reads issued early (latency hidden under exp/pack).
    bf16x8 vf[4][2];
    #pragma unroll
    for (int nt = 0; nt < 4; ++nt)
      #pragma unroll
      for (int kc = 0; kc < 2; ++kc) {
        const int sl = ((kc*4 + fq) ^ (fl & 7)) * 8;
        vf[nt][kc] = *(const bf16x8*)&Vt[p][(nt*16 + fl)*64 + sl];
      }

    // P = 2^S, RTZ bf16; lsum accumulates the SAME rounded value.
    // PsT[w][mt][k = nt*16+fl][q = fq*4 + 0..3] <- packed b64 (conflict-free).
    #pragma unroll
    for (int mt = 0; mt < 2; ++mt)
      #pragma unroll
      for (int nt = 0; nt < 4; ++nt) {
        unsigned u0 = __float_as_uint(__builtin_amdgcn_exp2f(s[mt][nt][0]));
        unsigned u1 = __float_as_uint(__builtin_amdgcn_exp2f(s[mt][nt][1]));
        unsigned u2 = __float_as_uint(__builtin_amdgcn_exp2f(s[mt][nt][2]));
        unsigned u3 = __float_as_uint(__builtin_amdgcn_exp2f(s[mt][nt][3]));
        lsum[mt][0] += __uint_as_float(u0 & 0xFFFF0000u);
        lsum[mt][1] += __uint_as_float(u1 & 0xFFFF0000u);
        lsum[mt][2] += __uint_as_float(u2 & 0xFFFF0000u);
        lsum[mt][3] += __uint_as_float(u3 & 0xFFFF0000u);
        u32x2 pw;
        pw[0] = (u0 >> 16) | (u1 & 0xFFFF0000u);
        pw[1] = (u2 >> 16) | (u3 & 0xFFFF0000u);
        *(u32x2*)&PsT[w][mt][nt*16 + fl][fq*4] = pw;
      }

    // Drain PsT stores before asm tr reads.
    asm volatile("s_waitcnt lgkmcnt(0)" ::: "memory");

    bf16x8 pf[2][2];
    #pragma unroll
    for (int mt = 0; mt < 2; ++mt)
      #pragma unroll
      for (int kc = 0; kc < 2; ++kc) {
        bf16x4 lo = tr64(ps_rd, mt*2048 + kc*1024);
        bf16x4 hi = tr64(ps_rd, mt*2048 + kc*1024 + 128);
        pf[mt][kc] = __builtin_shufflevector(lo, hi, 0, 1, 2, 3, 4, 5, 6, 7);
      }
    asm volatile("s_waitcnt lgkmcnt(0)" ::: "memory");
    __builtin_amdgcn_sched_barrier(0);   // rule 18: keep MFMAs below the wait

    __builtin_amdgcn_s_setprio(1);
    #pragma unroll
    for (int mt = 0; mt < 2; ++mt)
      #pragma unroll
      for (int nt = 0; nt < 4; ++nt) {
        oa[mt][nt] = __builtin_amdgcn_mfma_f32_16x16x32_bf16(
            pf[mt][0], vf[nt][0], oa[mt][nt], 0, 0, 0);
        oa[mt][nt] = __builtin_amdgcn_mfma_f32_16x16x32_bf16(
            pf[mt][1], vf[nt][1], oa[mt][nt], 0, 0, 0);
      }
    __builtin_amdgcn_s_setprio(0);

    // Next tile's stage (issued at top) has landed under the compute above;
    // drain it and release this buffer for overwrite in iter kt+2.
    asm volatile("s_waitcnt vmcnt(0)" ::: "memory");
    __builtin_amdgcn_s_barrier();
    __builtin_amdgcn_sched_barrier(0);
  }

  #pragma unroll
  for (int mt = 0; mt < 2; ++mt)
    #pragma unroll
    for (int r = 0; r < 4; ++r) {
      float v = lsum[mt][r];
      v += __shfl_xor(v, 1);
      v += __shfl_xor(v, 2);
      v += __shfl_xor(v, 4);
      v += __shfl_xor(v, 8);
      lsum[mt][r] = v;
    }

  #pragma unroll
  for (int mt = 0; mt < 2; ++mt)
    #pragma unroll
    for (int r = 0; r < 4; ++r) {
      int tok = b * TT + q0 + w*32 + mt*16 + fq*4 + r;
      int mk = mask[tok];
      float inv = 1.f / lsum[mt][r];
      size_t ro = (size_t)tok * CC + h * DD;
      #pragma unroll
      for (int nt = 0; nt < 4; ++nt) {
        float v = mk ? oa[mt][nt][r] * inv : 0.f;
        short lo, hi = bf_split(v, lo);
        obh[ro + nt*16 + fl] = hi;
        obl[ro + nt*16 + fl] = lo;
      }
    }
}

extern "C" void kernel_launch(void* const* d_in, const int* in_sizes, int n_in,
                              void* d_out, int out_size, void* d_ws, size_t ws_size,
                              hipStream_t stream) {
  const float* feats = (const float*)d_in[0];
  const int*   mask  = (const int*)d_in[1];
  const float* Wqkv  = (const float*)d_in[2];
  const float* Wp    = (const float*)d_in[3];
  const float* bp    = (const float*)d_in[4];
  float* out = (float*)d_out;

  short* qb   = (short*)d_ws;            // bf16 (b,h,t,d)
  short* kb   = qb + NX;                 // bf16 (b,h,t,d)
  short* vbt  = kb + NX;                 // bf16 (b,h,d,t)  TRANSPOSED
  short* S_hi = vbt + NX;                // x_hi, reused as o_hi after qkv
  short* S_lo = S_hi + NX;               // o_lo (attention epilogue)
  short* wqh  = S_lo + NX;
  short* wph  = wqh + NWQ;
  short* wpl  = wph + NWP;

  split_inputs<<<dim3(2048), dim3(256), 0, stream>>>(
      feats + (size_t)MM * CC, Wqkv, Wp, S_hi, wqh, wph, wpl, out);
  qkv_mfma<<<dim3(2304), dim3(256), 0, stream>>>(
      S_hi, wqh, mask, qb, kb, vbt);
  attn_mfma<<<dim3(96 * (TT/128)), dim3(256), 0, stream>>>(
      qb, kb, vbt, mask, S_hi, S_lo);
  proj_mfma<<<dim3(NTOK/128, CC/128), dim3(256), 0, stream>>>(
      S_hi, S_lo, wph, wpl, mask, bp, out);
}

// Round 15
// 212.020 us; speedup vs baseline: 1.0423x; 1.0423x over previous
//
#include <hip/hip_runtime.h>
#include <hip/hip_bf16.h>

// MaskedMSA: B=8, T=1024, C=768, H=12, D=64, M=8, N=8200
// R25: EXACT revert to R23/R21 (212.8/213.1us, twice-verified best).
//      R24 (64x128 qkv tile) regressed 221us: occupancy 30->47% but dur UP —
//      qkv is LDS-THROUGHPUT-bound; smaller tiles raise LDS reads/MFMA 1.5x
//      (reuse (BM+BN)/(BM*BN) is maximized at 64x64/wave) + conflicts 3.5->5.3M.
//      Full qkv design-space map (all measured): 128² serial 16KB = best;
//      dbuf/counted-vmcnt/B-direct/smaller-tile all regress. Pareto point.
//      Session ledger: 250.8 -> 212.8 via attn async-stage+raw-barriers (R13),
//      gemm swizzle + XCD grids (R14), PsT+tr64 (R16), attn parity-dbuf (R20),
//      setprio + split grid-stride (R21).

#define BB 8
#define TT 1024
#define CC 768
#define HH 12
#define DD 64
#define MM 8
#define NTOK (BB*TT)            // 8192
#define NX (NTOK*CC)            // 6291456
#define NWQ (3*CC*CC)           // 1769472
#define NWP (CC*CC)             // 589824
#define QSCALE 0.18033688011112042f   // 0.125 * log2(e)

typedef short bf16x4 __attribute__((ext_vector_type(4)));
typedef short bf16x8 __attribute__((ext_vector_type(8)));
typedef float f32x4  __attribute__((ext_vector_type(4)));
typedef float f32x16 __attribute__((ext_vector_type(16)));
typedef unsigned int u32x2 __attribute__((ext_vector_type(2)));

__device__ __forceinline__ void gld16(const void* g, void* l) {
  __builtin_amdgcn_global_load_lds(
      (const __attribute__((address_space(1))) void*)g,
      (__attribute__((address_space(3))) void*)l, 16, 0, 0);
}

// RNE fp32->bf16
__device__ __forceinline__ short bf_rne(float f) {
  unsigned u = __float_as_uint(f);
  return (short)((u + 0x7FFFu + ((u >> 16) & 1u)) >> 16);
}
// RNE fp32->bf16 hi, residual -> bf16 lo
__device__ __forceinline__ short bf_split(float f, short& lo) {
  unsigned u = __float_as_uint(f);
  unsigned hb = (u + 0x7FFFu + ((u >> 16) & 1u)) >> 16;
  float r = f - __uint_as_float(hb << 16);
  lo = bf_rne(r);
  return (short)hb;
}

// ------- split: x,Wqkv -> bf16 hi; Wp -> bf16 hi+lo; also zero out head -----
// Grid-stride at 2048 blocks (~4 items/thread).
__global__ __launch_bounds__(256) void split_inputs(
    const float* __restrict__ x, const float* __restrict__ wq,
    const float* __restrict__ wp,
    short* __restrict__ xh, short* __restrict__ wqh,
    short* __restrict__ wph, short* __restrict__ wpl,
    float* __restrict__ out) {
  const int G0 = NX/4, G1 = G0 + NWQ/4, G2 = G1 + NWP/4;
  const int i0 = blockIdx.x * 256 + threadIdx.x;
  if (i0 < MM*CC/4) {   // zero the first M rows of out (6144 floats)
    float4 z = {0.f, 0.f, 0.f, 0.f};
    ((float4*)out)[i0] = z;
  }
  for (int i = i0; i < G2; i += 2048 * 256) {
    if (i < G1) {
      const float* src = (i < G0) ? x : wq;
      short* dh = (i < G0) ? xh : wqh;
      int li = (i < G0) ? i : i - G0;
      float4 v = *(const float4*)(src + (size_t)li * 4);
      short4 h;
      h.x = bf_rne(v.x); h.y = bf_rne(v.y); h.z = bf_rne(v.z); h.w = bf_rne(v.w);
      *(short4*)(dh + (size_t)li * 4) = h;
    } else {
      int li = i - G1;
      float4 v = *(const float4*)(wp + (size_t)li * 4);
      short4 h, l;
      h.x = bf_split(v.x, l.x);
      h.y = bf_split(v.y, l.y);
      h.z = bf_split(v.z, l.z);
      h.w = bf_split(v.w, l.w);
      *(short4*)(wph + (size_t)li * 4) = h;
      *(short4*)(wpl + (size_t)li * 4) = l;
    }
  }
}

// ---------------- MFMA GEMM core (NT), 32x32x16; caller provides LDS --------
// LDS layout swizzle: physical slot (row, s) holds global 16B-slot s^((row>>1)&3).
template<bool TRIPLE>
__device__ __forceinline__ void gemm_core_768(
    const short* __restrict__ ah_g, const short* __restrict__ al_g,
    const short* __restrict__ bh_g, const short* __restrict__ bl_g,
    short* Ah, short* Al, short* Bh, short* Bl,
    int m0, int n0, f32x16 (&acc)[2][2],
    int& wm_o, int& wn_o) {
  const int tid = threadIdx.x;
  const int w = tid >> 6, ln = tid & 63;
  const int wm = (w >> 1) * 64, wn = (w & 1) * 64;
  const int sr = ln >> 2;
  const int sc = (((ln & 3) ^ ((ln >> 3) & 3))) * 8;   // swizzled source slot
  const int l31 = ln & 31, lhi = ln >> 5;
  const int key = (l31 >> 1) & 3;                      // == (row>>1)&3
  const int c0 = 2*w, c1 = 2*w + 1;
  const short* gAh0 = ah_g + (size_t)(m0 + c0*16 + sr)*CC + sc;
  const short* gAh1 = ah_g + (size_t)(m0 + c1*16 + sr)*CC + sc;
  const short* gBh0 = bh_g + (size_t)(n0 + c0*16 + sr)*CC + sc;
  const short* gBh1 = bh_g + (size_t)(n0 + c1*16 + sr)*CC + sc;
  const short* gAl0 = TRIPLE ? al_g + (size_t)(m0 + c0*16 + sr)*CC + sc : nullptr;
  const short* gAl1 = TRIPLE ? al_g + (size_t)(m0 + c1*16 + sr)*CC + sc : nullptr;
  const short* gBl0 = TRIPLE ? bl_g + (size_t)(n0 + c0*16 + sr)*CC + sc : nullptr;
  const short* gBl1 = TRIPLE ? bl_g + (size_t)(n0 + c1*16 + sr)*CC + sc : nullptr;
  #pragma unroll
  for (int i = 0; i < 2; i++)
    #pragma unroll
    for (int j = 0; j < 2; j++)
      #pragma unroll
      for (int r = 0; r < 16; r++) acc[i][j][r] = 0.f;

  for (int it = 0; it < 24; ++it) {
    const int ko = it * 32;
    gld16(gAh0 + ko, &Ah[c0*512]);
    gld16(gAh1 + ko, &Ah[c1*512]);
    gld16(gBh0 + ko, &Bh[c0*512]);
    gld16(gBh1 + ko, &Bh[c1*512]);
    if constexpr (TRIPLE) {
      gld16(gAl0 + ko, &Al[c0*512]);
      gld16(gAl1 + ko, &Al[c1*512]);
      gld16(gBl0 + ko, &Bl[c0*512]);
      gld16(gBl1 + ko, &Bl[c1*512]);
    }
    __syncthreads();
    bf16x8 a_h[2][2], b_h[2][2];
    #pragma unroll
    for (int t = 0; t < 2; ++t)
      #pragma unroll
      for (int kc = 0; kc < 2; ++kc) {
        const int sA = ((kc*2 + lhi) ^ key) * 8;
        a_h[t][kc] = *(const bf16x8*)&Ah[(wm + t*32 + l31)*32 + sA];
        b_h[t][kc] = *(const bf16x8*)&Bh[(wn + t*32 + l31)*32 + sA];
      }
    if constexpr (TRIPLE) {
      bf16x8 a_l[2][2], b_l[2][2];
      #pragma unroll
      for (int t = 0; t < 2; ++t)
        #pragma unroll
        for (int kc = 0; kc < 2; ++kc) {
          const int sA = ((kc*2 + lhi) ^ key) * 8;
          a_l[t][kc] = *(const bf16x8*)&Al[(wm + t*32 + l31)*32 + sA];
          b_l[t][kc] = *(const bf16x8*)&Bl[(wn + t*32 + l31)*32 + sA];
        }
      #pragma unroll
      for (int mt = 0; mt < 2; ++mt)
        #pragma unroll
        for (int nt = 0; nt < 2; ++nt)
          #pragma unroll
          for (int kc = 0; kc < 2; ++kc) {
            acc[mt][nt] = __builtin_amdgcn_mfma_f32_32x32x16_bf16(
                a_h[mt][kc], b_h[nt][kc], acc[mt][nt], 0, 0, 0);
            acc[mt][nt] = __builtin_amdgcn_mfma_f32_32x32x16_bf16(
                a_h[mt][kc], b_l[nt][kc], acc[mt][nt], 0, 0, 0);
            acc[mt][nt] = __builtin_amdgcn_mfma_f32_32x32x16_bf16(
                a_l[mt][kc], b_h[nt][kc], acc[mt][nt], 0, 0, 0);
          }
    } else {
      #pragma unroll
      for (int mt = 0; mt < 2; ++mt)
        #pragma unroll
        for (int nt = 0; nt < 2; ++nt)
          #pragma unroll
          for (int kc = 0; kc < 2; ++kc)
            acc[mt][nt] = __builtin_amdgcn_mfma_f32_32x32x16_bf16(
                a_h[mt][kc], b_h[nt][kc], acc[mt][nt], 0, 0, 0);
    }
    __syncthreads();
  }
  wm_o = wm; wn_o = wn;
}

// QKV (single-pass bf16): q (prescaled) / k natural (b,h,t,d);
// V computed with SWAPPED operands -> acc holds V^T -> vbt (b,h,d,t) direct.
// Grid transposed: x = m-block (XCD grouping), y = n-block.
__global__ __launch_bounds__(256) void qkv_mfma(
    const short* __restrict__ xh, const short* __restrict__ wqh,
    const int* __restrict__ mask,
    short* __restrict__ qb, short* __restrict__ kb, short* __restrict__ vbt) {
  __shared__ __align__(16) short Ah[128*32], Bh[128*32];   // 16 KB
  const int m0 = blockIdx.x * 128, n0 = blockIdx.y * 128;
  const int s = n0 / CC;          // 0:q 1:k 2:v (128-blocks don't straddle)
  f32x16 acc[2][2];
  int wm, wn;
  const int ln = threadIdx.x & 63;
  const int l31 = ln & 31, lhi = ln >> 5;

  if (s < 2) {
    gemm_core_768<false>(xh, nullptr, wqh, nullptr,
                         Ah, nullptr, Bh, nullptr, m0, n0, acc, wm, wn);
    short* dst = (s == 0) ? qb : kb;
    const float qs = (s == 0) ? QSCALE : 1.f;
    const int nb = n0 % CC;
    #pragma unroll
    for (int mt = 0; mt < 2; ++mt) {
      #pragma unroll
      for (int reg = 0; reg < 16; ++reg) {
        int row = m0 + wm + mt*32 + 4*lhi + (reg & 3) + 8*(reg >> 2);
        int mk = mask[row];
        int b = row >> 10, t = row & 1023;
        size_t rb = ((size_t)b * HH) * TT;
        #pragma unroll
        for (int nt = 0; nt < 2; ++nt) {
          int gnb = nb + wn + nt*32 + l31;
          int h = gnb >> 6, d = gnb & 63;
          float v = mk ? acc[mt][nt][reg] * qs : 0.f;
          dst[((rb + (size_t)h * TT) + t) * DD + d] = bf_rne(v);
        }
      }
    }
  } else {
    // swapped: A = Wv rows (m0'=n0 absolute Wqkv row), B = x tokens (n0'=m0)
    gemm_core_768<false>(wqh, nullptr, xh, nullptr,
                         Ah, nullptr, Bh, nullptr, n0, m0, acc, wm, wn);
    const int b = m0 >> 10, t0 = m0 & 1023;
    #pragma unroll
    for (int mt = 0; mt < 2; ++mt) {
      #pragma unroll
      for (int reg = 0; reg < 16; ++reg) {
        int f = (n0 - 2*CC) + wm + mt*32 + 4*lhi + (reg & 3) + 8*(reg >> 2);
        int h = f >> 6, d = f & 63;
        short* drow = vbt + (((size_t)(b*HH + h)*DD) + d)*TT + t0;
        #pragma unroll
        for (int nt = 0; nt < 2; ++nt) {
          int tk = wn + nt*32 + l31;
          int mk = mask[m0 + tk];
          drow[tk] = bf_rne(mk ? acc[mt][nt][reg] : 0.f);
        }
      }
    }
  }
}

// Proj (bf16x3): add bias, mask, write to out rows M..M+8191.
// Grid transposed: x = m-block (XCD grouping), y = n-block.
__global__ __launch_bounds__(256) void proj_mfma(
    const short* __restrict__ ah_g, const short* __restrict__ al_g,
    const short* __restrict__ bh_g, const short* __restrict__ bl_g,
    const int* __restrict__ mask, const float* __restrict__ bp,
    float* __restrict__ out) {
  __shared__ __align__(16) short Ah[128*32], Al[128*32];
  __shared__ __align__(16) short Bh[128*32], Bl[128*32];   // 32 KB
  const int m0 = blockIdx.x * 128, n0 = blockIdx.y * 128;
  f32x16 acc[2][2];
  int wm, wn;
  gemm_core_768<true>(ah_g, al_g, bh_g, bl_g, Ah, Al, Bh, Bl, m0, n0, acc, wm, wn);
  const int ln = threadIdx.x & 63;
  const int l31 = ln & 31, lhi = ln >> 5;
  #pragma unroll
  for (int mt = 0; mt < 2; ++mt) {
    #pragma unroll
    for (int reg = 0; reg < 16; ++reg) {
      int row = m0 + wm + mt*32 + 4*lhi + (reg & 3) + 8*(reg >> 2);
      int mk = mask[row];
      float* orow = out + (size_t)(MM + row) * CC;
      #pragma unroll
      for (int nt = 0; nt < 2; ++nt) {
        int gn = n0 + wn + nt*32 + l31;
        orow[gn] = mk ? acc[mt][nt][reg] + bp[gn] : 0.f;
      }
    }
  }
}

// ds_read_b64_tr_b16 with compile-time immediate offset.
__device__ __forceinline__ bf16x4 tr64(unsigned addr, int imm) {
  bf16x4 r;
  asm volatile("ds_read_b64_tr_b16 %0, %1 offset:%c2"
               : "=v"(r) : "v"(addr), "i"(imm));
  return r;
}

// ------- MFMA flash attention: parity-dbuf gld16 staging, 1 barrier/iter ----
// K/V LDS: linear [64 rows][64 cols] per buffer; physical 16B-slot s of row r
// holds global slot s^(r&7). Writer: gld16 lane-linear dest + pre-swizzled
// global source. Reader: slot = (kc*4+fq)^(fl&7) -> 8 lanes/bank-quad (floor).
// T5: s_setprio(1) around both MFMA clusters.
__global__ __launch_bounds__(256, 3) void attn_mfma(
    const short* __restrict__ qb, const short* __restrict__ kb,
    const short* __restrict__ vbt, const int* __restrict__ mask,
    short* __restrict__ obh, short* __restrict__ obl) {
  __shared__ __align__(16) short Ks[2][64*64];      // 16 KB
  __shared__ __align__(16) short Vt[2][64*64];      // 16 KB
  __shared__ __align__(16) short PsT[4][2][64][16]; // [w][mt][k][q] 16 KB
  const int tid = threadIdx.x, w = tid >> 6, ln = tid & 63;
  const int fl = ln & 15, fq = ln >> 4;
  const int i = blockIdx.x;
  const int bh = i % 96;                 // XCD-grouped (96 % 8 == 0)
  const int q0 = (i / 96) * 128;
  const int b = bh / HH, h = bh % HH;
  const size_t baseK = (size_t)bh * TT * DD;   // q,k natural (t,d)
  const size_t baseV = (size_t)bh * DD * TT;   // v transposed (d,t)

  bf16x8 qf[2][2];
  #pragma unroll
  for (int mt = 0; mt < 2; ++mt)
    #pragma unroll
    for (int kc = 0; kc < 2; ++kc)
      qf[mt][kc] = *(const bf16x8*)&qb[baseK +
          (size_t)(q0 + w*32 + mt*16 + fl) * DD + kc*32 + fq*8];

  f32x4 oa[2][4];
  float lsum[2][4];
  {
    f32x4 z = {0.f, 0.f, 0.f, 0.f};
    #pragma unroll
    for (int mt = 0; mt < 2; ++mt) {
      #pragma unroll
      for (int nt = 0; nt < 4; ++nt) oa[mt][nt] = z;
      #pragma unroll
      for (int r = 0; r < 4; ++r) lsum[mt][r] = 0.f;
    }
  }

  // tr-read base: per-lane addr = base(w) + fq*256 + fl*8 bytes; imm walks
  // mt (2048), kc (1024), half (128).
  const unsigned ps_rd =
      (unsigned)(size_t)(&PsT[0][0][0][0]) + w*4096 + fq*256 + fl*8;

  // Staging: thread tid covers row r1 = tid>>3 (instr1) and r2 = r1+32
  // (instr2), physical slot tid&7; global slot = (tid&7)^(r&7).
  const int r1 = tid >> 3, r2 = r1 + 32;
  const int g1 = ((ln & 7) ^ (r1 & 7)) * 8;   // shorts (tid&7 == ln&7)
  const int g2 = ((ln & 7) ^ (r2 & 7)) * 8;
  const short* kg1 = &kb[baseK + (size_t)r1 * DD + g1];
  const short* kg2 = &kb[baseK + (size_t)r2 * DD + g2];
  const short* vg1 = &vbt[baseV + (size_t)r1 * TT + g1];
  const short* vg2 = &vbt[baseV + (size_t)r2 * TT + g2];

  auto stage = [&](int p, int kt) {
    gld16(kg1 + (size_t)kt * 64 * DD, &Ks[p][w * 512]);
    gld16(kg2 + (size_t)kt * 64 * DD, &Ks[p][2048 + w * 512]);
    gld16(vg1 + kt * 64, &Vt[p][w * 512]);
    gld16(vg2 + kt * 64, &Vt[p][2048 + w * 512]);
  };

  // Prologue: tile 0 -> buf 0.
  stage(0, 0);
  asm volatile("s_waitcnt vmcnt(0)" ::: "memory");
  __builtin_amdgcn_s_barrier();
  __builtin_amdgcn_sched_barrier(0);

  for (int kt = 0; kt < 16; ++kt) {
    const int p = kt & 1;
    // Issue next tile's async stage into the idle buffer NOW.
    if (kt < 15) stage(p ^ 1, kt + 1);

    bf16x8 kf[4][2];
    #pragma unroll
    for (int nt = 0; nt < 4; ++nt)
      #pragma unroll
      for (int kc = 0; kc < 2; ++kc) {
        const int sl = ((kc*4 + fq) ^ (fl & 7)) * 8;
        kf[nt][kc] = *(const bf16x8*)&Ks[p][(nt*16 + fl)*64 + sl];
      }

    f32x4 s[2][4];
    {
      f32x4 z = {0.f, 0.f, 0.f, 0.f};
      #pragma unroll
      for (int mt = 0; mt < 2; ++mt)
        #pragma unroll
        for (int nt = 0; nt < 4; ++nt) s[mt][nt] = z;
    }
    __builtin_amdgcn_s_setprio(1);
    #pragma unroll
    for (int mt = 0; mt < 2; ++mt)
      #pragma unroll
      for (int nt = 0; nt < 4; ++nt) {
        s[mt][nt] = __builtin_amdgcn_mfma_f32_16x16x32_bf16(
            qf[mt][0], kf[nt][0], s[mt][nt], 0, 0, 0);
        s[mt][nt] = __builtin_amdgcn_mfma_f32_16x16x32_bf16(
            qf[mt][1], kf[nt][1], s[mt][nt], 0, 0, 0);
      }
    __builtin_amdgcn_s_setprio(0);

    // vf reads issued early (latency hidden under exp/pack).
    bf16x8 vf[4][2];
    #pragma unroll
    for (int nt = 0; nt < 4; ++nt)
      #pragma unroll
      for (int kc = 0; kc < 2; ++kc) {
        const int sl = ((kc*4 + fq) ^ (fl & 7)) * 8;
        vf[nt][kc] = *(const bf16x8*)&Vt[p][(nt*16 + fl)*64 + sl];
      }

    // P = 2^S, RTZ bf16; lsum accumulates the SAME rounded value.
    // PsT[w][mt][k = nt*16+fl][q = fq*4 + 0..3] <- packed b64 (conflict-free).
    #pragma unroll
    for (int mt = 0; mt < 2; ++mt)
      #pragma unroll
      for (int nt = 0; nt < 4; ++nt) {
        unsigned u0 = __float_as_uint(__builtin_amdgcn_exp2f(s[mt][nt][0]));
        unsigned u1 = __float_as_uint(__builtin_amdgcn_exp2f(s[mt][nt][1]));
        unsigned u2 = __float_as_uint(__builtin_amdgcn_exp2f(s[mt][nt][2]));
        unsigned u3 = __float_as_uint(__builtin_amdgcn_exp2f(s[mt][nt][3]));
        lsum[mt][0] += __uint_as_float(u0 & 0xFFFF0000u);
        lsum[mt][1] += __uint_as_float(u1 & 0xFFFF0000u);
        lsum[mt][2] += __uint_as_float(u2 & 0xFFFF0000u);
        lsum[mt][3] += __uint_as_float(u3 & 0xFFFF0000u);
        u32x2 pw;
        pw[0] = (u0 >> 16) | (u1 & 0xFFFF0000u);
        pw[1] = (u2 >> 16) | (u3 & 0xFFFF0000u);
        *(u32x2*)&PsT[w][mt][nt*16 + fl][fq*4] = pw;
      }

    // Drain PsT stores before asm tr reads.
    asm volatile("s_waitcnt lgkmcnt(0)" ::: "memory");

    bf16x8 pf[2][2];
    #pragma unroll
    for (int mt = 0; mt < 2; ++mt)
      #pragma unroll
      for (int kc = 0; kc < 2; ++kc) {
        bf16x4 lo = tr64(ps_rd, mt*2048 + kc*1024);
        bf16x4 hi = tr64(ps_rd, mt*2048 + kc*1024 + 128);
        pf[mt][kc] = __builtin_shufflevector(lo, hi, 0, 1, 2, 3, 4, 5, 6, 7);
      }
    asm volatile("s_waitcnt lgkmcnt(0)" ::: "memory");
    __builtin_amdgcn_sched_barrier(0);   // rule 18: keep MFMAs below the wait

    __builtin_amdgcn_s_setprio(1);
    #pragma unroll
    for (int mt = 0; mt < 2; ++mt)
      #pragma unroll
      for (int nt = 0; nt < 4; ++nt) {
        oa[mt][nt] = __builtin_amdgcn_mfma_f32_16x16x32_bf16(
            pf[mt][0], vf[nt][0], oa[mt][nt], 0, 0, 0);
        oa[mt][nt] = __builtin_amdgcn_mfma_f32_16x16x32_bf16(
            pf[mt][1], vf[nt][1], oa[mt][nt], 0, 0, 0);
      }
    __builtin_amdgcn_s_setprio(0);

    // Next tile's stage (issued at top) has landed under the compute above;
    // drain it and release this buffer for overwrite in iter kt+2.
    asm volatile("s_waitcnt vmcnt(0)" ::: "memory");
    __builtin_amdgcn_s_barrier();
    __builtin_amdgcn_sched_barrier(0);
  }

  #pragma unroll
  for (int mt = 0; mt < 2; ++mt)
    #pragma unroll
    for (int r = 0; r < 4; ++r) {
      float v = lsum[mt][r];
      v += __shfl_xor(v, 1);
      v += __shfl_xor(v, 2);
      v += __shfl_xor(v, 4);
      v += __shfl_xor(v, 8);
      lsum[mt][r] = v;
    }

  #pragma unroll
  for (int mt = 0; mt < 2; ++mt)
    #pragma unroll
    for (int r = 0; r < 4; ++r) {
      int tok = b * TT + q0 + w*32 + mt*16 + fq*4 + r;
      int mk = mask[tok];
      float inv = 1.f / lsum[mt][r];
      size_t ro = (size_t)tok * CC + h * DD;
      #pragma unroll
      for (int nt = 0; nt < 4; ++nt) {
        float v = mk ? oa[mt][nt][r] * inv : 0.f;
        short lo, hi = bf_split(v, lo);
        obh[ro + nt*16 + fl] = hi;
        obl[ro + nt*16 + fl] = lo;
      }
    }
}

extern "C" void kernel_launch(void* const* d_in, const int* in_sizes, int n_in,
                              void* d_out, int out_size, void* d_ws, size_t ws_size,
                              hipStream_t stream) {
  const float* feats = (const float*)d_in[0];
  const int*   mask  = (const int*)d_in[1];
  const float* Wqkv  = (const float*)d_in[2];
  const float* Wp    = (const float*)d_in[3];
  const float* bp    = (const float*)d_in[4];
  float* out = (float*)d_out;

  short* qb   = (short*)d_ws;            // bf16 (b,h,t,d)
  short* kb   = qb + NX;                 // bf16 (b,h,t,d)
  short* vbt  = kb + NX;                 // bf16 (b,h,d,t)  TRANSPOSED
  short* S_hi = vbt + NX;                // x_hi, reused as o_hi after qkv
  short* S_lo = S_hi + NX;               // o_lo (attention epilogue)
  short* wqh  = S_lo + NX;
  short* wph  = wqh + NWQ;
  short* wpl  = wph + NWP;

  split_inputs<<<dim3(2048), dim3(256), 0, stream>>>(
      feats + (size_t)MM * CC, Wqkv, Wp, S_hi, wqh, wph, wpl, out);
  qkv_mfma<<<dim3(NTOK/128, 3*CC/128), dim3(256), 0, stream>>>(
      S_hi, wqh, mask, qb, kb, vbt);
  attn_mfma<<<dim3(96 * (TT/128)), dim3(256), 0, stream>>>(
      qb, kb, vbt, mask, S_hi, S_lo);
  proj_mfma<<<dim3(NTOK/128, CC/128), dim3(256), 0, stream>>>(
      S_hi, S_lo, wph, wpl, mask, bp, out);
}